// Round 2
// baseline (277.343 us; speedup 1.0000x reference)
//
#include <hip/hip_runtime.h>
#include <hip/hip_bf16.h>

// GCNConv: out[i] = sum_{e: row[e]=i} dis[row]*dis[col]*xl[col] + dis[i]^2*xl[i]
// N=50000, E=1.6M, D=128, fp32 in/out.
//
// R16 -> R17: post-mortem showed k_reduce is L2-miss-traffic bound (FETCH
// 152MB @ 3.5TB/s = the whole 51us; near compulsory floor of 8 XCD x 12.8MB).
// The lever was the ~100us of sort machinery (k_binjoint+k_split). Replaced
// the 2-level LDS counting sort with a direct global-atomic padded-CSR build:
//   k_prep:  zero cnt_row/cnt_col, transpose W to bf16
//   k_fill:  per edge: p=atomicAdd(cnt_row[row]); ecol[row*PAD+p]=col;
//            atomicAdd(cnt_col[col])            (~3.2M L2 atomics, ~10us)
//   k_gemmd: MFMA 64x128 tile, epilogue y = bf16(dis[row]*(xW+b)) with
//            dis[row]=rsqrt(cnt_col+1) computed inline; writes dis[] too
//   k_reduce: unchanged R16 gather (beg=i*PAD, end=beg+cnt_row[i])
// begN/endN/ebuf/cebuf/scan all deleted. PAD=128 = 4x mean degree
// (overflow drops edges, same guard semantics as old CAP check; P~e-84).

#define D     128

typedef short  bf16x8 __attribute__((ext_vector_type(8)));
typedef float  f32x4  __attribute__((ext_vector_type(4)));
typedef unsigned short us4 __attribute__((ext_vector_type(4)));
typedef unsigned short us8 __attribute__((ext_vector_type(8)));

static __device__ __forceinline__ unsigned short f2bf(float f) {
    unsigned u = __float_as_uint(f);
    u = (u + 0x7FFFu + ((u >> 16) & 1u)) >> 16;   // RNE
    return (unsigned short)u;
}
static __device__ __forceinline__ float bf2f(unsigned short s) {
    return __uint_as_float(((unsigned)s) << 16);
}

// --- init: zero counters, wtb = bf16(W^T) --------------------------------
__global__ __launch_bounds__(256) void k_prep(const float* __restrict__ W,
                                              unsigned short* __restrict__ wtb,
                                              int* __restrict__ cnt_row,
                                              int* __restrict__ cnt_col,
                                              int N) {
    int i = blockIdx.x * 256 + threadIdx.x;
    if (i < N) { cnt_row[i] = 0; cnt_col[i] = 0; }
    if (i < D * D) {
        int n = i >> 7, k = i & 127;
        wtb[n * 128 + k] = f2bf(W[k * 128 + n]);
    }
}

// --- padded-CSR build + col-degree, one pass over edges ------------------
__global__ __launch_bounds__(256) void k_fill(const int* __restrict__ rows,
                                              const int* __restrict__ cols,
                                              int* __restrict__ cnt_row,
                                              int* __restrict__ cnt_col,
                                              unsigned short* __restrict__ ecol,
                                              int E, int PAD) {
    int e0 = (blockIdx.x * 256 + threadIdx.x) << 2;
    if (e0 >= E) return;
    if (e0 + 4 <= E) {
        const int4 r = *(const int4*)&rows[e0];
        const int4 c = *(const int4*)&cols[e0];
        int p;
        p = atomicAdd(&cnt_row[r.x], 1);
        if (p < PAD) ecol[(size_t)r.x * PAD + p] = (unsigned short)c.x;
        atomicAdd(&cnt_col[c.x], 1);
        p = atomicAdd(&cnt_row[r.y], 1);
        if (p < PAD) ecol[(size_t)r.y * PAD + p] = (unsigned short)c.y;
        atomicAdd(&cnt_col[c.y], 1);
        p = atomicAdd(&cnt_row[r.z], 1);
        if (p < PAD) ecol[(size_t)r.z * PAD + p] = (unsigned short)c.z;
        atomicAdd(&cnt_col[c.z], 1);
        p = atomicAdd(&cnt_row[r.w], 1);
        if (p < PAD) ecol[(size_t)r.w * PAD + p] = (unsigned short)c.w;
        atomicAdd(&cnt_col[c.w], 1);
    } else {
        for (int e = e0; e < E; ++e) {
            int r = rows[e], c = cols[e];
            int p = atomicAdd(&cnt_row[r], 1);
            if (p < PAD) ecol[(size_t)r * PAD + p] = (unsigned short)c;
            atomicAdd(&cnt_col[c], 1);
        }
    }
}

// --- MFMA gemm 64x128 tile; epilogue premultiplies by dis[row] -----------
__global__ __launch_bounds__(1024) void k_gemmd(
        const float* __restrict__ x, const unsigned short* __restrict__ wtb,
        const float* __restrict__ bia, const int* __restrict__ cnt_col,
        float* __restrict__ dis, unsigned short* __restrict__ xlb, int N) {
    __shared__ __align__(16) unsigned char smem[52224];
    unsigned short (*wt)[136] = (unsigned short (*)[136])smem;            // 34816 B
    unsigned short (*xs)[136] = (unsigned short (*)[136])(smem + 34816);  // 17408 B
    const int t = threadIdx.x;
    const int row0 = blockIdx.x * 64;
    #pragma unroll
    for (int i = 0; i < 2; ++i) {         // W^T: 2048 ushort8 chunks
        int j = i * 1024 + t;
        int n = j >> 4, k8 = j & 15;
        us8 v = *(const us8*)&wtb[j * 8];
        *(us8*)&wt[n][k8 * 8] = v;
    }
    #pragma unroll
    for (int i = 0; i < 2; ++i) {         // x: 2048 float4 -> ushort4
        int j = i * 1024 + t;
        int r = j >> 5, c4 = j & 31;
        int gr = row0 + r;
        us4 o = (us4){0, 0, 0, 0};
        if (gr < N) {
            float4 v = *(const float4*)&x[(size_t)gr * D + c4 * 4];
            o = (us4){f2bf(v.x), f2bf(v.y), f2bf(v.z), f2bf(v.w)};
        }
        *(us4*)&xs[r][c4 * 4] = o;
    }
    if (t >= 256 && t < 320) {            // dis[] for this block's rows
        int rr = row0 + (t - 256);
        if (rr < N) dis[rr] = rsqrtf((float)(cnt_col[rr] + 1));
    }
    __syncthreads();
    if (t < 256) {
        const int w  = t >> 6, l = t & 63;
        const int m0 = w * 16;
        const int lm = l & 15, lq = l >> 4;
        f32x4 acc[8];
        #pragma unroll
        for (int nt = 0; nt < 8; ++nt) acc[nt] = (f32x4){0.f, 0.f, 0.f, 0.f};
        #pragma unroll
        for (int kk = 0; kk < 4; ++kk) {
            const int kof = kk * 32 + lq * 8;
            bf16x8 a = *(const bf16x8*)&xs[m0 + lm][kof];
            #pragma unroll
            for (int nt = 0; nt < 8; ++nt) {
                bf16x8 bb = *(const bf16x8*)&wt[nt * 16 + lm][kof];
                acc[nt] = __builtin_amdgcn_mfma_f32_16x16x32_bf16(a, bb, acc[nt], 0, 0, 0);
            }
        }
        float bc[8];
        #pragma unroll
        for (int nt = 0; nt < 8; ++nt) bc[nt] = bia[nt * 16 + lm];
        #pragma unroll
        for (int r = 0; r < 4; ++r) {
            int grow = row0 + m0 + lq * 4 + r;
            if (grow < N) {
                float dv = rsqrtf((float)(cnt_col[grow] + 1));
                #pragma unroll
                for (int nt = 0; nt < 8; ++nt) {
                    int col = nt * 16 + lm;
                    xlb[(size_t)grow * D + col] = f2bf(dv * (acc[nt][r] + bc[nt]));
                }
            }
        }
    }
}

// --- wave-per-node gather-reduce: 2 edges/load, ping-pong prefetch -------
// xlb holds y = dis*xl. out[i] = dis[i] * (y[i] + sum_{c in N(i)} y[c]).
__global__ __launch_bounds__(256) void k_reduce(const int* __restrict__ cnt_row,
                                                const unsigned short* __restrict__ ecol,
                                                const float* __restrict__ dis,
                                                const unsigned short* __restrict__ xlb,
                                                float* __restrict__ out, int N, int PAD) {
    const int wave = threadIdx.x >> 6;
    const int lane = threadIdx.x & 63;
    const int half = lane >> 5;          // which edge of the pair this lane serves
    const int l32  = lane & 31;          // 32 lanes x ushort4 = one 256B row
    const int i = blockIdx.x * 4 + wave;
    if (i >= N) return;

    float a0, a1, a2, a3;
    {   // self loop: y[i]; only half 0 contributes (halves are summed at the end)
        us4 sv = *(const us4*)&xlb[(size_t)i * D + (l32 << 2)];
        float s = (half == 0) ? 1.0f : 0.0f;
        a0 = s * bf2f(sv[0]); a1 = s * bf2f(sv[1]);
        a2 = s * bf2f(sv[2]); a3 = s * bf2f(sv[3]);
    }
    const int beg = i * PAD;
    int cnt = cnt_row[i]; if (cnt > PAD) cnt = PAD;
    const int end = beg + cnt;

#define FETCH(V, J) do { \
    _Pragma("unroll") \
    for (int u = 0; u < 8; ++u) { \
        int cc = __shfl(c, (J) + 2 * u + half); \
        V[u] = *(const us4*)&xlb[((size_t)cc << 7) + (l32 << 2)]; \
    } } while (0)
#define CFULL(V) do { \
    _Pragma("unroll") \
    for (int u = 0; u < 8; ++u) { \
        a0 += bf2f(V[u][0]); a1 += bf2f(V[u][1]); \
        a2 += bf2f(V[u][2]); a3 += bf2f(V[u][3]); \
    } } while (0)
#define CTAIL(V, J) do { \
    _Pragma("unroll") \
    for (int u = 0; u < 8; ++u) { \
        float w = ((J) + 2 * u + half < m) ? 1.0f : 0.0f; \
        a0 = fmaf(w, bf2f(V[u][0]), a0); a1 = fmaf(w, bf2f(V[u][1]), a1); \
        a2 = fmaf(w, bf2f(V[u][2]), a2); a3 = fmaf(w, bf2f(V[u][3]), a3); \
    } } while (0)

    for (int base = beg; base < end; base += 64) {
        int m = end - base; if (m > 64) m = 64;
        int c = 0;
        if (lane < m) c = ecol[base + lane];   // inactive lanes: row 0 (masked later)
        us4 A[8], B[8];
        int j = 0;
        FETCH(A, 0);                           // group = 8 pairs = 16 edges
        for (; j + 32 <= m; j += 32) {
            FETCH(B, j + 16);                  // issue next before consuming A
            CFULL(A);
            if (j + 32 < m) FETCH(A, j + 32);
            CFULL(B);
        }
        int rem = m - j;                       // 0 < rem < 32 => A fetched at j
        if (rem > 0) {
            if (rem > 16) { FETCH(B, j + 16); CFULL(A); CTAIL(B, j + 16); }
            else          { CTAIL(A, j); }
        }
    }
#undef FETCH
#undef CFULL
#undef CTAIL

    // merge the two halves (each covered alternating edges of same columns)
    a0 += __shfl_xor(a0, 32);
    a1 += __shfl_xor(a1, 32);
    a2 += __shfl_xor(a2, 32);
    a3 += __shfl_xor(a3, 32);
    if (half == 0) {
        const float di = dis[i];
        *(float4*)&out[(size_t)i * D + (l32 << 2)] =
            make_float4(di * a0, di * a1, di * a2, di * a3);
    }
}

// ======================= fallback (R1 atomic path) =======================
__global__ __launch_bounds__(256) void k_zero(int* __restrict__ p, int n) {
    int i = blockIdx.x * 256 + threadIdx.x;
    if (i < n) p[i] = 0;
}
__global__ __launch_bounds__(256) void k_deg(const int* __restrict__ cols,
                                             int* __restrict__ cntc, int E) {
    int e = blockIdx.x * 256 + threadIdx.x;
    if (e < E) atomicAdd(&cntc[cols[e]], 1);
}
__global__ __launch_bounds__(256) void k_dis(const int* __restrict__ cntc,
                                             float* __restrict__ dis, int N) {
    int i = blockIdx.x * 256 + threadIdx.x;
    if (i < N) dis[i] = rsqrtf((float)(cntc[i] + 1));
}
#define GEMM_R 8
__global__ __launch_bounds__(128) void k_gemmf(const float* __restrict__ x,
                                               const float* __restrict__ W,
                                               const float* __restrict__ b,
                                               float* __restrict__ xl, int N) {
    __shared__ float xs[GEMM_R][D];
    const int c  = threadIdx.x;
    const int r0 = blockIdx.x * GEMM_R;
    #pragma unroll
    for (int r = 0; r < GEMM_R; ++r) {
        int row = r0 + r;
        xs[r][c] = (row < N) ? x[row * D + c] : 0.0f;
    }
    __syncthreads();
    float acc[GEMM_R];
    const float bc = b[c];
    #pragma unroll
    for (int r = 0; r < GEMM_R; ++r) acc[r] = bc;
    for (int k = 0; k < D; k += 4) {
        const float w0 = W[(k + 0) * D + c];
        const float w1 = W[(k + 1) * D + c];
        const float w2 = W[(k + 2) * D + c];
        const float w3 = W[(k + 3) * D + c];
        #pragma unroll
        for (int r = 0; r < GEMM_R; ++r) {
            const float4 xv = *reinterpret_cast<const float4*>(&xs[r][k]);
            acc[r] = fmaf(xv.x, w0, acc[r]);
            acc[r] = fmaf(xv.y, w1, acc[r]);
            acc[r] = fmaf(xv.z, w2, acc[r]);
            acc[r] = fmaf(xv.w, w3, acc[r]);
        }
    }
    #pragma unroll
    for (int r = 0; r < GEMM_R; ++r) {
        int row = r0 + r;
        if (row < N) xl[row * D + c] = acc[r];
    }
}
__global__ __launch_bounds__(256) void k_self(const float* __restrict__ xl,
                                              const float* __restrict__ dis,
                                              float* __restrict__ out, int N) {
    int gid = blockIdx.x * 256 + threadIdx.x;
    int i = gid >> 7;
    if (i < N) {
        float d = dis[i];
        out[gid] = d * d * xl[gid];
    }
}
__global__ __launch_bounds__(256) void k_scatter(const int* __restrict__ rows,
                                                 const int* __restrict__ cols,
                                                 const float* __restrict__ dis,
                                                 const float* __restrict__ xl,
                                                 float* __restrict__ out, int E) {
    long long gid = (long long)blockIdx.x * 256 + threadIdx.x;
    int e    = (int)(gid >> 6);
    int lane = (int)(gid & 63);
    if (e >= E) return;
    const int row = rows[e];
    const int col = cols[e];
    const float nrm = dis[row] * dis[col];
    atomicAdd(&out[row * D + lane],      nrm * xl[col * D + lane]);
    atomicAdd(&out[row * D + 64 + lane], nrm * xl[col * D + 64 + lane]);
}

// ======================= launch ==========================================
extern "C" void kernel_launch(void* const* d_in, const int* in_sizes, int n_in,
                              void* d_out, int out_size, void* d_ws, size_t ws_size,
                              hipStream_t stream) {
    const float* x   = (const float*)d_in[0];
    const int*   ei  = (const int*)d_in[1];
    const float* W   = (const float*)d_in[2];
    const float* b   = (const float*)d_in[3];
    float*       out = (float*)d_out;

    const int N = in_sizes[0] / D;   // 50000
    const int E = in_sizes[1] / 2;   // 1.6M
    const int* rows = ei;
    const int* cols = ei + E;

    // PAD = 4x mean degree, >=128, multiple of 64 (overflow edges dropped,
    // P ~ e^-84 for Poisson(32) at PAD=128)
    int mean = (E + N - 1) / N;
    int PAD = ((4 * mean + 63) / 64) * 64;
    if (PAD < 128) PAD = 128;

    // ws layout
    char* p = (char*)d_ws;
    size_t off = 0;
    unsigned short* xlb     = (unsigned short*)(p + off); off += (size_t)N * D * 2;
    unsigned short* wtb     = (unsigned short*)(p + off); off += (size_t)D * D * 2;
    float*          dis     = (float*)(p + off);          off += (size_t)N * 4;
    int*            cnt_row = (int*)(p + off);            off += (size_t)N * 4;
    int*            cnt_col = (int*)(p + off);            off += (size_t)N * 4;
    unsigned short* ecol    = (unsigned short*)(p + off); off += (size_t)N * PAD * 2;

    const int gN = (N + 255) / 256;
    const int gE = (E + 255) / 256;

    if (N <= 65536 && ws_size >= off) {
        int gP = (N > D * D ? N : D * D);
        k_prep  <<<(gP + 255) / 256, 256, 0, stream>>>(W, wtb, cnt_row, cnt_col, N);
        k_fill  <<<(E + 1023) / 1024, 256, 0, stream>>>(rows, cols, cnt_row, cnt_col, ecol, E, PAD);
        k_gemmd <<<(N + 63) / 64, 1024, 0, stream>>>(x, wtb, b, cnt_col, dis, xlb, N);
        k_reduce<<<(N + 3) / 4, 256, 0, stream>>>(cnt_row, ecol, dis, xlb, out, N, PAD);
    } else {
        // fallback: R1 atomic scatter path (fp32 xl)
        char* q = (char*)d_ws;
        float* xl   = (float*)q;
        float* disF = (float*)(q + (size_t)N * D * 4);
        int*   cc   = (int*)(q + (size_t)N * D * 4 + (size_t)N * 4);
        k_zero <<<gN, 256, 0, stream>>>(cc, N);
        k_deg  <<<gE, 256, 0, stream>>>(cols, cc, E);
        k_dis  <<<gN, 256, 0, stream>>>(cc, disF, N);
        k_gemmf<<<(N + GEMM_R - 1) / GEMM_R, 128, 0, stream>>>(x, W, b, xl, N);
        k_self <<<((N * D) + 255) / 256, 256, 0, stream>>>(xl, disF, out, N);
        long long st = (long long)E * 64;
        k_scatter<<<(int)((st + 255) / 256), 256, 0, stream>>>(rows, cols, disF, xl, out, E);
    }
}